// Round 2
// 729.975 us; speedup vs baseline: 1.0286x; 1.0286x over previous
//
#include <hip/hip_runtime.h>

// SE block, all fp32: x(64,128,112,112) -> global avg pool -> MLP(128->32->128,
// relu, hard-sigmoid) -> channel-wise scale.
// Memory-bound. Naive traffic: read x twice + write out = ~1.23 GB -> ~196 us floor.
// This version harvests the 256 MB Infinity Cache across the pool->scale boundary:
//   - se_scale walks planes in REVERSE dispatch order, so its first blocks re-read
//     the planes se_pool streamed last (still L3-resident; L3 is memory-side and
//     survives kernel boundaries).
//   - out is written with nontemporal stores so the 411 MB write stream does not
//     write-allocate in L3 and evict the x window before it is re-read.

#define C_IN  128
#define C_MID 32
#define HW    12544          // 112*112
#define NVEC4 (HW / 4)       // 3136 float4 per plane

// clang native 4-float vector: accepted by __builtin_nontemporal_store
// (HIP's float4 is a class type and is rejected).
typedef float vfloat4 __attribute__((ext_vector_type(4)));

// ---------------- Kernel 1: global average pool per (b,c) plane ----------------
__global__ __launch_bounds__(256) void se_pool(const float* __restrict__ x,
                                               float* __restrict__ s) {
    const int plane = blockIdx.x;                       // plane = b*C_IN + c
    const vfloat4* xv = (const vfloat4*)(x + (size_t)plane * HW);
    float acc = 0.0f;
    for (int v = threadIdx.x; v < NVEC4; v += 256) {
        vfloat4 d = xv[v];
        acc += (d.x + d.y) + (d.z + d.w);
    }
    // wave (64-lane) reduce
    #pragma unroll
    for (int off = 32; off > 0; off >>= 1) acc += __shfl_down(acc, off, 64);
    __shared__ float red[4];
    if ((threadIdx.x & 63) == 0) red[threadIdx.x >> 6] = acc;
    __syncthreads();
    if (threadIdx.x == 0)
        s[plane] = (red[0] + red[1] + red[2] + red[3]) * (1.0f / (float)HW);
}

// ---------------- Kernel 2: excite MLP + hard sigmoid (tiny) ----------------
// grid = B (64), block = C_IN (128)
__global__ __launch_bounds__(128) void se_excite(const float* __restrict__ s,
                                                 const float* __restrict__ w1,
                                                 const float* __restrict__ b1,
                                                 const float* __restrict__ w2,
                                                 const float* __restrict__ b2,
                                                 float* __restrict__ g) {
    const int b = blockIdx.x;
    const int t = threadIdx.x;
    __shared__ float sh_s[C_IN];
    __shared__ float sh_h[C_MID];
    sh_s[t] = s[b * C_IN + t];
    __syncthreads();
    if (t < C_MID) {
        float acc = b1[t];
        #pragma unroll 8
        for (int c = 0; c < C_IN; ++c)
            acc += sh_s[c] * w1[t * C_IN + c];        // w1[m][c], row-major (C_MID,C_IN)
        sh_h[t] = fmaxf(acc, 0.0f);
    }
    __syncthreads();
    float acc = b2[t];
    #pragma unroll
    for (int m = 0; m < C_MID; ++m)
        acc += sh_h[m] * w2[t * C_MID + m];           // w2[c][m], row-major (C_IN,C_MID)
    g[b * C_IN + t] = fminf(fmaxf(0.2f * acc + 0.5f, 0.0f), 1.0f);
}

// ---------------- Kernel 3: channel-wise scale (reverse order, NT stores) ----------------
__global__ __launch_bounds__(256) void se_scale(const float* __restrict__ x,
                                                const float* __restrict__ g,
                                                float* __restrict__ out) {
    // Reverse plane order: first-dispatched blocks touch the planes se_pool read
    // LAST -> those are the ones still resident in the 256 MB Infinity Cache.
    const int plane = (int)gridDim.x - 1 - (int)blockIdx.x;
    const float gate = g[plane];
    const vfloat4* xv = (const vfloat4*)(x + (size_t)plane * HW);
    vfloat4* ov = (vfloat4*)(out + (size_t)plane * HW);
    for (int v = threadIdx.x; v < NVEC4; v += 256) {
        vfloat4 d = xv[v];
        d *= gate;
        // Nontemporal: don't let the output stream write-allocate in L3 and evict
        // the x window we're still harvesting.
        __builtin_nontemporal_store(d, &ov[v]);
    }
}

extern "C" void kernel_launch(void* const* d_in, const int* in_sizes, int n_in,
                              void* d_out, int out_size, void* d_ws, size_t ws_size,
                              hipStream_t stream) {
    const float* x  = (const float*)d_in[0];
    const float* w1 = (const float*)d_in[1];
    const float* b1 = (const float*)d_in[2];
    const float* w2 = (const float*)d_in[3];
    const float* b2 = (const float*)d_in[4];
    float* out = (float*)d_out;

    const int planes = in_sizes[0] / HW;   // B * C_IN = 8192
    const int B = planes / C_IN;           // 64

    float* s = (float*)d_ws;               // planes floats (means)
    float* g = s + planes;                 // planes floats (gates)

    se_pool<<<planes, 256, 0, stream>>>(x, s);
    se_excite<<<B, C_IN, 0, stream>>>(s, w1, b1, w2, b2, g);
    se_scale<<<planes, 256, 0, stream>>>(x, g, out);
}